// Round 5
// baseline (150.766 us; speedup 1.0000x reference)
//
#include <hip/hip_runtime.h>
#include <cstddef>

// RetNetAttention round 5: 256-tile double-buffered MFMA GEMMs (prefetch-1-tile-ahead,
// single barrier/K-tile, T2 swizzle, T5 setprio). Middle section unchanged from R4.
#define NB 2
#define NL 4096
#define ND 1024
#define NH 16
#define DKH 64
#define CK 64
#define NCH (NL / CK)
#define NM (NB * NL)
#define KD 1024
#define NT (KD / 64)

typedef __attribute__((ext_vector_type(8))) short bf16x8;
typedef __attribute__((ext_vector_type(4))) float f32x4;

__device__ __forceinline__ float dsigmoid(float x) { return 1.0f / (1.0f + __expf(-x)); }
__device__ __forceinline__ float bf2f(unsigned short u) { return __uint_as_float((unsigned)u << 16); }
__device__ __forceinline__ unsigned short f2bf(float f) {
    unsigned u = __float_as_uint(f);
    u = (u + 0x7fffu + ((u >> 16) & 1u)) >> 16;
    return (unsigned short)u;
}
// element index into [R][64]-ushort tile, XOR-swizzled at 8-elem (16B) granularity
__device__ __forceinline__ int swz(int row, int col) { return row * 64 + (col ^ ((row & 7) << 3)); }

__device__ __forceinline__ void gload16(const void* g, void* l) {
    __builtin_amdgcn_global_load_lds(
        (const __attribute__((address_space(1))) unsigned int*)g,
        (__attribute__((address_space(3))) unsigned int*)l, 16, 0, 0);
}

// ================= fused fp32 -> bf16 casts =================
__global__ __launch_bounds__(256)
void k_cast_all(const float* __restrict__ x, const float* __restrict__ Wq,
                const float* __restrict__ Wo, unsigned short* __restrict__ xb,
                unsigned short* __restrict__ Wqb, unsigned short* __restrict__ Wob)
{
    const int N1 = NB * NL * ND / 4;
    const int N2 = 3 * ND * ND / 4;
    const int N3 = ND * ND / 4;
    const int total = N1 + N2 + N3;
    int i = blockIdx.x * 256 + threadIdx.x;
    const int stride = gridDim.x * 256;
    for (; i < total; i += stride) {
        const float4* src;
        ushort4* dst;
        int j;
        if (i < N1)            { src = (const float4*)x;  dst = (ushort4*)xb;  j = i; }
        else if (i < N1 + N2)  { src = (const float4*)Wq; dst = (ushort4*)Wqb; j = i - N1; }
        else                   { src = (const float4*)Wo; dst = (ushort4*)Wob; j = i - N1 - N2; }
        float4 v = src[j];
        ushort4 o;
        o.x = f2bf(v.x); o.y = f2bf(v.y); o.z = f2bf(v.z); o.w = f2bf(v.w);
        dst[j] = o;
    }
}

// ====== QKV GEMM: 256x256 tile, BK=64, 8 waves (2Mx4N), dbuf + prefetch-1-tile ======
__global__ __launch_bounds__(512, 2)
void k_gemm_qkv_256(const unsigned short* __restrict__ A, const unsigned short* __restrict__ Bm,
                    unsigned short* __restrict__ Qb, unsigned short* __restrict__ Kb,
                    unsigned short* __restrict__ Vb)
{
    __shared__ unsigned short As[2][256 * 64];   // 64 KB
    __shared__ unsigned short Bs[2][256 * 64];   // 64 KB
    const int tid = threadIdx.x;
    const int w = tid >> 6, lane = tid & 63;
    const int wm = w >> 2, wn = w & 3;
    const int lr = lane & 15, lk = lane >> 4;

    // T1 bijective XCD swizzle (nwg = 384, %8==0)
    const int nbx = gridDim.x;
    const int nwg = nbx * gridDim.y;
    const int bid = blockIdx.y * nbx + blockIdx.x;
    const int sb  = (bid & 7) * (nwg >> 3) + (bid >> 3);
    const int row0 = (sb / nbx) * 256, col0 = (sb % nbx) * 256;

    const int srow = tid >> 3;                   // 0..63
    const int schk = (tid & 7) ^ (srow & 7);     // pre-swizzled source chunk
    const unsigned short* gA = A + (size_t)(row0 + srow) * KD + schk * 8;
    const unsigned short* gB = Bm + (size_t)(col0 + srow) * KD + schk * 8;
    const int ldst = w * 512;                    // wave-uniform LDS dest (elements)

    f32x4 acc[8][4];
#pragma unroll
    for (int m = 0; m < 8; ++m)
#pragma unroll
        for (int n = 0; n < 4; ++n) acc[m][n] = (f32x4){0.f, 0.f, 0.f, 0.f};

    int arow[8], brow[4];
#pragma unroll
    for (int m = 0; m < 8; ++m) arow[m] = (wm * 128 + m * 16 + lr) * 64;
#pragma unroll
    for (int n = 0; n < 4; ++n) brow[n] = (wn * 64 + n * 16 + lr) * 64;
    const int xr = lr & 7;
    const int co0 = ((0 * 4 + lk) ^ xr) * 8;
    const int co1 = ((1 * 4 + lk) ^ xr) * 8;

#define STAGE_QKV(t, pb)                                                          \
    do {                                                                          \
        _Pragma("unroll")                                                         \
        for (int i_ = 0; i_ < 4; ++i_)                                            \
            gload16(gA + (size_t)(i_ * 64) * KD + (t) * 64, &As[pb][ldst + i_ * 4096]); \
        _Pragma("unroll")                                                         \
        for (int i_ = 0; i_ < 4; ++i_)                                            \
            gload16(gB + (size_t)(i_ * 64) * KD + (t) * 64, &Bs[pb][ldst + i_ * 4096]); \
    } while (0)

    STAGE_QKV(0, 0);
    __syncthreads();
    for (int t = 0; t < NT; ++t) {
        const int cur = t & 1;
        if (t + 1 < NT) STAGE_QKV(t + 1, cur ^ 1);
        bf16x8 bfr[4][2];
#pragma unroll
        for (int n = 0; n < 4; ++n) {
            bfr[n][0] = *(const bf16x8*)&Bs[cur][brow[n] + co0];
            bfr[n][1] = *(const bf16x8*)&Bs[cur][brow[n] + co1];
        }
#pragma unroll
        for (int p = 0; p < 4; ++p) {
            bf16x8 a[2][2];
#pragma unroll
            for (int mm = 0; mm < 2; ++mm) {
                a[mm][0] = *(const bf16x8*)&As[cur][arow[p * 2 + mm] + co0];
                a[mm][1] = *(const bf16x8*)&As[cur][arow[p * 2 + mm] + co1];
            }
            __builtin_amdgcn_s_setprio(1);
#pragma unroll
            for (int s = 0; s < 2; ++s)
#pragma unroll
                for (int mm = 0; mm < 2; ++mm)
#pragma unroll
                    for (int n = 0; n < 4; ++n)
                        acc[p * 2 + mm][n] = __builtin_amdgcn_mfma_f32_16x16x32_bf16(
                            a[mm][s], bfr[n][s], acc[p * 2 + mm][n], 0, 0, 0);
            __builtin_amdgcn_s_setprio(0);
        }
        __syncthreads();
    }
#undef STAGE_QKV

#pragma unroll
    for (int m = 0; m < 8; ++m) {
        const int mrow0 = row0 + wm * 128 + m * 16 + lk * 4;
#pragma unroll
        for (int n = 0; n < 4; ++n) {
            const int gcol = col0 + wn * 64 + n * 16 + lr;
            const int three = gcol >> 10;
            const int h = (gcol >> 6) & (NH - 1);
            const int d = gcol & (DKH - 1);
            unsigned short* dst = (three == 0) ? Qb : ((three == 1) ? Kb : Vb);
#pragma unroll
            for (int j = 0; j < 4; ++j) {
                const int mr = mrow0 + j;
                const int b = mr >> 12;
                const int t = mr & (NL - 1);
                dst[(((size_t)b * NH + h) * NL + t) * DKH + d] = f2bf(acc[m][n][j]);
            }
        }
    }
}

// ====== output GEMM: 256x128 tile, BK=64, 8 waves (4Mx2N), dbuf + prefetch-1-tile ======
__global__ __launch_bounds__(512, 2)
void k_gemm_out_256(const unsigned short* __restrict__ A, const unsigned short* __restrict__ Bm,
                    float* __restrict__ C)
{
    __shared__ unsigned short As[2][256 * 64];   // 64 KB
    __shared__ unsigned short Bs[2][128 * 64];   // 32 KB
    const int tid = threadIdx.x;
    const int w = tid >> 6, lane = tid & 63;
    const int wm = w >> 1, wn = w & 1;
    const int lr = lane & 15, lk = lane >> 4;

    const int nbx = gridDim.x;                   // 8
    const int nwg = nbx * gridDim.y;             // 256
    const int bid = blockIdx.y * nbx + blockIdx.x;
    const int sb  = (bid & 7) * (nwg >> 3) + (bid >> 3);
    const int row0 = (sb / nbx) * 256, col0 = (sb % nbx) * 128;

    const int srow = tid >> 3;
    const int schk = (tid & 7) ^ (srow & 7);
    const unsigned short* gA = A + (size_t)(row0 + srow) * KD + schk * 8;
    const unsigned short* gB = Bm + (size_t)(col0 + srow) * KD + schk * 8;
    const int ldst = w * 512;

    f32x4 acc[4][4];
#pragma unroll
    for (int m = 0; m < 4; ++m)
#pragma unroll
        for (int n = 0; n < 4; ++n) acc[m][n] = (f32x4){0.f, 0.f, 0.f, 0.f};

    int arow[4], brow[4];
#pragma unroll
    for (int m = 0; m < 4; ++m) arow[m] = (wm * 64 + m * 16 + lr) * 64;
#pragma unroll
    for (int n = 0; n < 4; ++n) brow[n] = (wn * 64 + n * 16 + lr) * 64;
    const int xr = lr & 7;
    const int co0 = ((0 * 4 + lk) ^ xr) * 8;
    const int co1 = ((1 * 4 + lk) ^ xr) * 8;

#define STAGE_OUT(t, pb)                                                          \
    do {                                                                          \
        _Pragma("unroll")                                                         \
        for (int i_ = 0; i_ < 4; ++i_)                                            \
            gload16(gA + (size_t)(i_ * 64) * KD + (t) * 64, &As[pb][ldst + i_ * 4096]); \
        _Pragma("unroll")                                                         \
        for (int i_ = 0; i_ < 2; ++i_)                                            \
            gload16(gB + (size_t)(i_ * 64) * KD + (t) * 64, &Bs[pb][ldst + i_ * 4096]); \
    } while (0)

    STAGE_OUT(0, 0);
    __syncthreads();
    for (int t = 0; t < NT; ++t) {
        const int cur = t & 1;
        if (t + 1 < NT) STAGE_OUT(t + 1, cur ^ 1);
        bf16x8 bfr[4][2];
#pragma unroll
        for (int n = 0; n < 4; ++n) {
            bfr[n][0] = *(const bf16x8*)&Bs[cur][brow[n] + co0];
            bfr[n][1] = *(const bf16x8*)&Bs[cur][brow[n] + co1];
        }
#pragma unroll
        for (int p = 0; p < 4; ++p) {
            bf16x8 a[2];
            a[0] = *(const bf16x8*)&As[cur][arow[p] + co0];
            a[1] = *(const bf16x8*)&As[cur][arow[p] + co1];
            __builtin_amdgcn_s_setprio(1);
#pragma unroll
            for (int s = 0; s < 2; ++s)
#pragma unroll
                for (int n = 0; n < 4; ++n)
                    acc[p][n] = __builtin_amdgcn_mfma_f32_16x16x32_bf16(
                        a[s], bfr[n][s], acc[p][n], 0, 0, 0);
            __builtin_amdgcn_s_setprio(0);
        }
        __syncthreads();
    }
#undef STAGE_OUT

#pragma unroll
    for (int m = 0; m < 4; ++m) {
        const int mrow0 = row0 + wm * 64 + m * 16 + lk * 4;
#pragma unroll
        for (int n = 0; n < 4; ++n) {
            const int gcol = col0 + wn * 64 + n * 16 + lr;
#pragma unroll
            for (int j = 0; j < 4; ++j)
                C[(size_t)(mrow0 + j) * ND + gcol] = acc[m][n][j];
        }
    }
}

// ====== per-chunk local state (LN fused): SL[d][e] = sum_s g^{63-s} v_s[d] ln(k_s)[e] ======
__global__ __launch_bounds__(256)
void k_chunk_state(const unsigned short* __restrict__ Kb, const unsigned short* __restrict__ Vb,
                   const float* __restrict__ lg, unsigned short* __restrict__ SL)
{
    __shared__ unsigned short Kt[64 * 64];
    __shared__ unsigned short Vt[64 * 64];
    __shared__ float red[64][8];
    const int blk = blockIdx.x;
    const int c   = blk & (NCH - 1);
    const int bh  = blk >> 6;
    const int h   = bh & (NH - 1);
    const float gamma = dsigmoid(lg[h]);
    const float l2g = log2f(gamma);
    const int tid = threadIdx.x;
    const unsigned short* Kc = Kb + ((size_t)bh * NL + c * CK) * DKH;
    const unsigned short* Vc = Vb + ((size_t)bh * NL + c * CK) * DKH;

    const int r  = tid & 63;
    const int w4 = tid >> 6;
    const int c0 = w4 * 8;
    bf16x8 k8a = *(const bf16x8*)(Kc + (size_t)r * DKH + c0);
    bf16x8 k8b = *(const bf16x8*)(Kc + (size_t)r * DKH + c0 + 32);
    bf16x8 v8a = *(const bf16x8*)(Vc + (size_t)r * DKH + c0);
    bf16x8 v8b = *(const bf16x8*)(Vc + (size_t)r * DKH + c0 + 32);
    float sum = 0.f, sq = 0.f;
#pragma unroll
    for (int j = 0; j < 8; ++j) {
        float xa = bf2f((unsigned short)k8a[j]); sum += xa; sq += xa * xa;
        float xb = bf2f((unsigned short)k8b[j]); sum += xb; sq += xb * xb;
    }
    red[r][w4] = sum; red[r][w4 + 4] = sq;
    __syncthreads();
    float s  = red[r][0] + red[r][1] + red[r][2] + red[r][3];
    float qq = red[r][4] + red[r][5] + red[r][6] + red[r][7];
    float mu = s * (1.0f / 64.0f);
    float rstd = rsqrtf(qq * (1.0f / 64.0f) - mu * mu + 1e-5f);
    float wgt = exp2f((float)(CK - 1 - r) * l2g);
#pragma unroll
    for (int j = 0; j < 8; ++j) {
        Kt[swz(c0 + j, r)]      = f2bf((bf2f((unsigned short)k8a[j]) - mu) * rstd);
        Kt[swz(c0 + 32 + j, r)] = f2bf((bf2f((unsigned short)k8b[j]) - mu) * rstd);
        Vt[swz(c0 + j, r)]      = f2bf(bf2f((unsigned short)v8a[j]) * wgt);
        Vt[swz(c0 + 32 + j, r)] = f2bf(bf2f((unsigned short)v8b[j]) * wgt);
    }
    __syncthreads();

    const int w = tid >> 6, lane = tid & 63;
    const int wr = w >> 1, wc = w & 1;
    const int lr = lane & 15, lk = lane >> 4;
    f32x4 acc[2][2];
#pragma unroll
    for (int m = 0; m < 2; ++m)
#pragma unroll
        for (int n = 0; n < 2; ++n) acc[m][n] = (f32x4){0.f, 0.f, 0.f, 0.f};
#pragma unroll
    for (int kk = 0; kk < 2; ++kk) {
        const int so = kk * 32 + lk * 8;
        bf16x8 a[2], b[2];
#pragma unroll
        for (int m = 0; m < 2; ++m) a[m] = *(const bf16x8*)&Vt[swz(wr * 32 + m * 16 + lr, so)];
#pragma unroll
        for (int n = 0; n < 2; ++n) b[n] = *(const bf16x8*)&Kt[swz(wc * 32 + n * 16 + lr, so)];
#pragma unroll
        for (int m = 0; m < 2; ++m)
#pragma unroll
            for (int n = 0; n < 2; ++n)
                acc[m][n] = __builtin_amdgcn_mfma_f32_16x16x32_bf16(a[m], b[n], acc[m][n], 0, 0, 0);
    }

    unsigned short* out = SL + (size_t)blk * (DKH * DKH);
#pragma unroll
    for (int m = 0; m < 2; ++m)
#pragma unroll
        for (int n = 0; n < 2; ++n)
#pragma unroll
            for (int j = 0; j < 4; ++j) {
                int d = wr * 32 + m * 16 + lk * 4 + j;
                int e = wc * 32 + n * 16 + lr;
                out[d * DKH + e] = f2bf(acc[m][n][j]);
            }
}

// ====== sequential scan over chunks: SS[c] = state BEFORE chunk c ======
__global__ __launch_bounds__(256)
void k_scan(const unsigned short* __restrict__ SL, const float* __restrict__ lg,
            unsigned short* __restrict__ SS)
{
    const int bh = blockIdx.x;
    const int qt = blockIdx.y;
    const int h  = bh & (NH - 1);
    const float gamma = dsigmoid(lg[h]);
    const float dc = __powf(gamma, (float)CK);
    const size_t base = (size_t)bh * NCH * (DKH * DKH) + qt * 1024 + threadIdx.x * 4;
    float s0 = 0.f, s1 = 0.f, s2 = 0.f, s3 = 0.f;
    for (int c = 0; c < NCH; ++c) {
        const size_t off = base + (size_t)c * (DKH * DKH);
        ushort4 l = *(const ushort4*)(SL + off);
        ushort4 o;
        o.x = f2bf(s0); o.y = f2bf(s1); o.z = f2bf(s2); o.w = f2bf(s3);
        *(ushort4*)(SS + off) = o;
        s0 = s0 * dc + bf2f(l.x); s1 = s1 * dc + bf2f(l.y);
        s2 = s2 * dc + bf2f(l.z); s3 = s3 * dc + bf2f(l.w);
    }
}

// ====== per-chunk output (LN fused): Y = mask(Q K^T)V + g^{t+1} Q S^T, coalesced bf16 out ======
__global__ __launch_bounds__(256)
void k_chunk_out(const unsigned short* __restrict__ Qb, const unsigned short* __restrict__ Kb,
                 const unsigned short* __restrict__ Vb, const unsigned short* __restrict__ SS,
                 const float* __restrict__ lg, unsigned short* __restrict__ Y)
{
    __shared__ unsigned short Qs[64 * 64];
    __shared__ unsigned short Ks[64 * 64];
    __shared__ unsigned short Vt[64 * 64];
    __shared__ unsigned short Ss[64 * 64];
    __shared__ unsigned short Ps[64 * 64];   // reused as Y-staging
    __shared__ float red[64][8];
    const int blk = blockIdx.x;
    const int c   = blk & (NCH - 1);
    const int bh  = blk >> 6;
    const int h   = bh & (NH - 1);
    const int b   = bh >> 4;
    const float gamma = dsigmoid(lg[h]);
    const float l2g = log2f(gamma);
    const int tid = threadIdx.x;
    const unsigned short* Qc = Qb + ((size_t)bh * NL + c * CK) * DKH;
    const unsigned short* Kc = Kb + ((size_t)bh * NL + c * CK) * DKH;
    const unsigned short* Vc = Vb + ((size_t)bh * NL + c * CK) * DKH;
    const unsigned short* Sc = SS + (size_t)blk * (DKH * DKH);

    const int r  = tid & 63;
    const int w4 = tid >> 6;
    const int c0 = w4 * 8;
    bf16x8 q8a = *(const bf16x8*)(Qc + (size_t)r * DKH + c0);
    bf16x8 q8b = *(const bf16x8*)(Qc + (size_t)r * DKH + c0 + 32);
    bf16x8 k8a = *(const bf16x8*)(Kc + (size_t)r * DKH + c0);
    bf16x8 k8b = *(const bf16x8*)(Kc + (size_t)r * DKH + c0 + 32);
    bf16x8 v8a = *(const bf16x8*)(Vc + (size_t)r * DKH + c0);
    bf16x8 v8b = *(const bf16x8*)(Vc + (size_t)r * DKH + c0 + 32);
    bf16x8 s8a = *(const bf16x8*)(Sc + (size_t)r * DKH + c0);
    bf16x8 s8b = *(const bf16x8*)(Sc + (size_t)r * DKH + c0 + 32);
    float sum = 0.f, sq = 0.f;
#pragma unroll
    for (int j = 0; j < 8; ++j) {
        float xa = bf2f((unsigned short)k8a[j]); sum += xa; sq += xa * xa;
        float xb = bf2f((unsigned short)k8b[j]); sum += xb; sq += xb * xb;
    }
    red[r][w4] = sum; red[r][w4 + 4] = sq;
    __syncthreads();
    float sm = red[r][0] + red[r][1] + red[r][2] + red[r][3];
    float qq = red[r][4] + red[r][5] + red[r][6] + red[r][7];
    float mu = sm * (1.0f / 64.0f);
    float rstd = rsqrtf(qq * (1.0f / 64.0f) - mu * mu + 1e-5f);
    *(bf16x8*)&Qs[swz(r, c0)]      = q8a;
    *(bf16x8*)&Qs[swz(r, c0 + 32)] = q8b;
    *(bf16x8*)&Ss[swz(r, c0)]      = s8a;
    *(bf16x8*)&Ss[swz(r, c0 + 32)] = s8b;
#pragma unroll
    for (int j = 0; j < 8; ++j) {
        Ks[swz(r, c0 + j)]      = f2bf((bf2f((unsigned short)k8a[j]) - mu) * rstd);
        Ks[swz(r, c0 + 32 + j)] = f2bf((bf2f((unsigned short)k8b[j]) - mu) * rstd);
        Vt[swz(c0 + j, r)]      = (unsigned short)v8a[j];
        Vt[swz(c0 + 32 + j, r)] = (unsigned short)v8b[j];
    }
    __syncthreads();

    const int w = tid >> 6, lane = tid & 63;
    const int wr = w >> 1, wc = w & 1;
    const int lr = lane & 15, lk = lane >> 4;

    // phase A: P = Q K^T with causal decay
    f32x4 accp[2][2];
#pragma unroll
    for (int m = 0; m < 2; ++m)
#pragma unroll
        for (int n = 0; n < 2; ++n) accp[m][n] = (f32x4){0.f, 0.f, 0.f, 0.f};
#pragma unroll
    for (int kk = 0; kk < 2; ++kk) {
        const int eo = kk * 32 + lk * 8;
        bf16x8 a[2], bfr[2];
#pragma unroll
        for (int m = 0; m < 2; ++m) a[m]   = *(const bf16x8*)&Qs[swz(wr * 32 + m * 16 + lr, eo)];
#pragma unroll
        for (int n = 0; n < 2; ++n) bfr[n] = *(const bf16x8*)&Ks[swz(wc * 32 + n * 16 + lr, eo)];
#pragma unroll
        for (int m = 0; m < 2; ++m)
#pragma unroll
            for (int n = 0; n < 2; ++n)
                accp[m][n] = __builtin_amdgcn_mfma_f32_16x16x32_bf16(a[m], bfr[n], accp[m][n], 0, 0, 0);
    }
#pragma unroll
    for (int m = 0; m < 2; ++m)
#pragma unroll
        for (int n = 0; n < 2; ++n)
#pragma unroll
            for (int j = 0; j < 4; ++j) {
                int t = wr * 32 + m * 16 + lk * 4 + j;
                int s = wc * 32 + n * 16 + lr;
                int dt = t - s;
                float v = (dt >= 0) ? accp[m][n][j] * exp2f((float)dt * l2g) : 0.0f;
                Ps[swz(t, s)] = f2bf(v);
            }
    __syncthreads();

    // phase B
    f32x4 accy[2][2], accz[2][2];
#pragma unroll
    for (int m = 0; m < 2; ++m)
#pragma unroll
        for (int n = 0; n < 2; ++n) {
            accy[m][n] = (f32x4){0.f, 0.f, 0.f, 0.f};
            accz[m][n] = (f32x4){0.f, 0.f, 0.f, 0.f};
        }
#pragma unroll
    for (int kk = 0; kk < 2; ++kk) {
        const int so = kk * 32 + lk * 8;
        bf16x8 pa[2], qa[2], vb[2], sb[2];
#pragma unroll
        for (int m = 0; m < 2; ++m) {
            pa[m] = *(const bf16x8*)&Ps[swz(wr * 32 + m * 16 + lr, so)];
            qa[m] = *(const bf16x8*)&Qs[swz(wr * 32 + m * 16 + lr, so)];
        }
#pragma unroll
        for (int n = 0; n < 2; ++n) {
            vb[n] = *(const bf16x8*)&Vt[swz(wc * 32 + n * 16 + lr, so)];
            sb[n] = *(const bf16x8*)&Ss[swz(wc * 32 + n * 16 + lr, so)];
        }
#pragma unroll
        for (int m = 0; m < 2; ++m)
#pragma unroll
            for (int n = 0; n < 2; ++n) {
                accy[m][n] = __builtin_amdgcn_mfma_f32_16x16x32_bf16(pa[m], vb[n], accy[m][n], 0, 0, 0);
                accz[m][n] = __builtin_amdgcn_mfma_f32_16x16x32_bf16(qa[m], sb[n], accz[m][n], 0, 0, 0);
            }
    }
    __syncthreads();   // Ps reads done; safe to overwrite as Y-staging

#pragma unroll
    for (int m = 0; m < 2; ++m)
#pragma unroll
        for (int n = 0; n < 2; ++n)
#pragma unroll
            for (int j = 0; j < 4; ++j) {
                int t = wr * 32 + m * 16 + lk * 4 + j;
                int d = wc * 32 + n * 16 + lr;
                float g = exp2f((float)(t + 1) * l2g);
                Ps[swz(t, d)] = f2bf(accy[m][n][j] + g * accz[m][n][j]);
            }
    __syncthreads();

    // coalesced write: each row = 128B contiguous
#pragma unroll
    for (int i = 0; i < 2; ++i) {
        int f  = tid + i * 256;
        int rr = f >> 3;
        int ch = f & 7;
        bf16x8 val = *(const bf16x8*)&Ps[swz(rr, ch * 8)];
        unsigned short* p = Y + ((size_t)(b * NL + c * CK + rr)) * ND + h * DKH + ch * 8;
        *(bf16x8*)p = val;
    }
}

extern "C" void kernel_launch(void* const* d_in, const int* in_sizes, int n_in,
                              void* d_out, int out_size, void* d_ws, size_t ws_size,
                              hipStream_t stream)
{
    (void)in_sizes; (void)n_in; (void)out_size; (void)ws_size;
    const float* x  = (const float*)d_in[0];
    const float* Wq = (const float*)d_in[1];
    const float* Wo = (const float*)d_in[2];
    const float* lg = (const float*)d_in[3];
    float* out = (float*)d_out;

    const size_t SZ = (size_t)NB * NH * NL * DKH;
    unsigned short* xb  = (unsigned short*)d_ws;
    unsigned short* Wqb = xb + SZ;
    unsigned short* Wob = Wqb + (size_t)3 * ND * ND;
    unsigned short* Qb  = Wob + (size_t)ND * ND;
    unsigned short* Kb  = Qb + SZ;
    unsigned short* Vb  = Kb + SZ;
    unsigned short* SL  = Vb + SZ;
    unsigned short* SS  = SL + SZ;
    unsigned short* Ybb = SS + SZ;

    k_cast_all<<<2048, 256, 0, stream>>>(x, Wq, Wo, xb, Wqb, Wob);
    k_gemm_qkv_256<<<dim3(3 * ND / 256, NM / 256), 512, 0, stream>>>(xb, Wqb, Qb, Kb, Vb);
    k_chunk_state<<<dim3(NB * NH * NCH), 256, 0, stream>>>(Kb, Vb, lg, SL);
    k_scan<<<dim3(NB * NH, 4), 256, 0, stream>>>(SL, lg, SS);
    k_chunk_out<<<dim3(NB * NH * NCH), 256, 0, stream>>>(Qb, Kb, Vb, SS, lg, Ybb);
    k_gemm_out_256<<<dim3(ND / 128, NM / 256), 512, 0, stream>>>(Ybb, Wob, out);
}

// Round 6
// 144.076 us; speedup vs baseline: 1.0464x; 1.0464x over previous
//
#include <hip/hip_runtime.h>
#include <cstddef>

// RetNetAttention round 6: qkv GEMM ported to 8-phase counted-vmcnt schedule
// (T3+T4+T5, 256x256, BK=64, B reg-pipelined). Rest identical to round 4.
#define NB 2
#define NL 4096
#define ND 1024
#define NH 16
#define DKH 64
#define CK 64
#define NCH (NL / CK)
#define NM (NB * NL)
#define KD 1024
#define NTK (KD / 64)   // 16 K-tiles

typedef __attribute__((ext_vector_type(8))) short bf16x8;
typedef __attribute__((ext_vector_type(4))) float f32x4;

__device__ __forceinline__ float dsigmoid(float x) { return 1.0f / (1.0f + __expf(-x)); }
__device__ __forceinline__ float bf2f(unsigned short u) { return __uint_as_float((unsigned)u << 16); }
__device__ __forceinline__ unsigned short f2bf(float f) {
    unsigned u = __float_as_uint(f);
    u = (u + 0x7fffu + ((u >> 16) & 1u)) >> 16;
    return (unsigned short)u;
}
__device__ __forceinline__ int swz(int row, int col) { return row * 64 + (col ^ ((row & 7) << 3)); }

__device__ __forceinline__ void gload16(const void* g, void* l) {
    __builtin_amdgcn_global_load_lds(
        (const __attribute__((address_space(1))) unsigned int*)g,
        (__attribute__((address_space(3))) unsigned int*)l, 16, 0, 0);
}

template<int N> __device__ __forceinline__ void vmw() {
    if constexpr (N == 0) asm volatile("s_waitcnt vmcnt(0)" ::: "memory");
    else if constexpr (N == 1) asm volatile("s_waitcnt vmcnt(1)" ::: "memory");
    else if constexpr (N == 2) asm volatile("s_waitcnt vmcnt(2)" ::: "memory");
    else if constexpr (N == 3) asm volatile("s_waitcnt vmcnt(3)" ::: "memory");
    else if constexpr (N == 4) asm volatile("s_waitcnt vmcnt(4)" ::: "memory");
    else if constexpr (N == 5) asm volatile("s_waitcnt vmcnt(5)" ::: "memory");
    else if constexpr (N == 6) asm volatile("s_waitcnt vmcnt(6)" ::: "memory");
}

// ================= fused fp32 -> bf16 casts =================
__global__ __launch_bounds__(256)
void k_cast_all(const float* __restrict__ x, const float* __restrict__ Wq,
                const float* __restrict__ Wo, unsigned short* __restrict__ xb,
                unsigned short* __restrict__ Wqb, unsigned short* __restrict__ Wob)
{
    const int N1 = NB * NL * ND / 4;
    const int N2 = 3 * ND * ND / 4;
    const int N3 = ND * ND / 4;
    const int total = N1 + N2 + N3;
    int i = blockIdx.x * 256 + threadIdx.x;
    const int stride = gridDim.x * 256;
    for (; i < total; i += stride) {
        const float4* src;
        ushort4* dst;
        int j;
        if (i < N1)            { src = (const float4*)x;  dst = (ushort4*)xb;  j = i; }
        else if (i < N1 + N2)  { src = (const float4*)Wq; dst = (ushort4*)Wqb; j = i - N1; }
        else                   { src = (const float4*)Wo; dst = (ushort4*)Wob; j = i - N1 - N2; }
        float4 v = src[j];
        ushort4 o;
        o.x = f2bf(v.x); o.y = f2bf(v.y); o.z = f2bf(v.z); o.w = f2bf(v.w);
        dst[j] = o;
    }
}

// ====== QKV GEMM: 256x256 tile, BK=64, 8-phase counted-vmcnt schedule ======
// Waves: 8, each owns all 256 M-rows x 32 N-cols (acc[16][2]).
// Per K-tile t, phase j (j=0..3):
//   ds_read a-frags (A-group j of tile t, staged 4 slots ago)
//   waves (w>>1)==j: ds_read B-regs for tile t+1 from Bbuf[(t+1)&1]
//   stage A-group j of t+1 -> Abuf[(t+1)&1]; B-group j of t+2 -> Bbuf[t&1]
//   vmcnt(6)  (retires the slot read NEXT phase; never drains)
//   barrier; lgkmcnt(0); sched_barrier; setprio(1); 16 MFMA; setprio(0); barrier
__global__ __launch_bounds__(512, 1)
void k_gemm_qkv_8p(const unsigned short* __restrict__ A, const unsigned short* __restrict__ Bm,
                   unsigned short* __restrict__ Qb, unsigned short* __restrict__ Kb,
                   unsigned short* __restrict__ Vb)
{
    __shared__ unsigned short Abuf[2][256 * 64];   // 64 KB
    __shared__ unsigned short Bbuf[2][256 * 64];   // 64 KB
    const int tid = threadIdx.x;
    const int w = tid >> 6, lane = tid & 63;
    const int lr = lane & 15, lk = lane >> 4;

    // T1 bijective XCD swizzle (nwg = 384, %8==0)
    const int nbx = gridDim.x;
    const int nwg = nbx * gridDim.y;
    const int bid = blockIdx.y * nbx + blockIdx.x;
    const int sb  = (bid & 7) * (nwg >> 3) + (bid >> 3);
    const int row0 = (sb / nbx) * 256, col0 = (sb % nbx) * 256;

    // staging: wave w covers rows [8w, 8w+8) of each 64-row group; lane l -> row 8w+(l>>3), chunk l&7
    const int srow8 = lane >> 3;
    const int schk  = (lane & 7) ^ srow8;          // pre-swizzled source chunk (dest row &7 == srow8)
    const unsigned short* gAr = A  + (size_t)(row0 + 8 * w + srow8) * KD + schk * 8;
    const unsigned short* gBr = Bm + (size_t)(col0 + 8 * w + srow8) * KD + schk * 8;

#define STA(g, t, pb) gload16(gAr + (size_t)(64 * (g)) * KD + (size_t)(t) * 64, \
                              &Abuf[pb][(64 * (g) + 8 * w) * 64])
#define STB(g, t, pb) gload16(gBr + (size_t)(64 * (g)) * KD + (size_t)((t) + 2) * 64, \
                              &Bbuf[pb][(64 * (g) + 8 * w) * 64])

    const int xr  = lr & 7;
    const int co0 = ((0 * 4 + lk) ^ xr) * 8;
    const int co1 = ((1 * 4 + lk) ^ xr) * 8;
    const int brow0 = (32 * w + lr) * 64;          // B n-frag 0
    const int brow1 = (32 * w + 16 + lr) * 64;     // B n-frag 1

    f32x4 acc[16][2];
#pragma unroll
    for (int m = 0; m < 16; ++m)
#pragma unroll
        for (int n = 0; n < 2; ++n) acc[m][n] = (f32x4){0.f, 0.f, 0.f, 0.f};

    // ---- prologue: A-of-0 -> Abuf[0], B-of-0 -> Bbuf[0], B-of-1 -> Bbuf[1]
#pragma unroll
    for (int g = 0; g < 4; ++g) STA(g, 0, 0);
#pragma unroll
    for (int g = 0; g < 4; ++g) STB(g, -2, 0);     // cols 0..63  (t+2 = 0)
#pragma unroll
    for (int g = 0; g < 4; ++g) STB(g, -1, 1);     // cols 64..127 (t+2 = 1)
    vmw<0>();
    __builtin_amdgcn_s_barrier();

    bf16x8 br0[2][2], br1[2][2];
    br0[0][0] = *(const bf16x8*)&Bbuf[0][brow0 + co0];
    br0[0][1] = *(const bf16x8*)&Bbuf[0][brow0 + co1];
    br0[1][0] = *(const bf16x8*)&Bbuf[0][brow1 + co0];
    br0[1][1] = *(const bf16x8*)&Bbuf[0][brow1 + co1];
    asm volatile("s_waitcnt lgkmcnt(0)" ::: "memory");
    __builtin_amdgcn_s_barrier();                   // br0 reads done before tile0's STB lands

#define PH(j, cur, nxt, BRC, BRN, DO_STA, DO_STB, DO_BR, VMN, tt)                  \
    {                                                                              \
        bf16x8 af[4][2];                                                           \
        _Pragma("unroll") for (int i_ = 0; i_ < 4; ++i_) {                         \
            af[i_][0] = *(const bf16x8*)&Abuf[cur][(16 * (4 * (j) + i_) + lr) * 64 + co0]; \
            af[i_][1] = *(const bf16x8*)&Abuf[cur][(16 * (4 * (j) + i_) + lr) * 64 + co1]; \
        }                                                                          \
        if ((DO_BR) && (w >> 1) == (j)) {                                          \
            BRN[0][0] = *(const bf16x8*)&Bbuf[nxt][brow0 + co0];                   \
            BRN[0][1] = *(const bf16x8*)&Bbuf[nxt][brow0 + co1];                   \
            BRN[1][0] = *(const bf16x8*)&Bbuf[nxt][brow1 + co0];                   \
            BRN[1][1] = *(const bf16x8*)&Bbuf[nxt][brow1 + co1];                   \
        }                                                                          \
        if (DO_STA) STA(j, (tt) + 1, nxt);                                         \
        if (DO_STB) STB(j, (tt), cur);                                             \
        vmw<VMN>();                                                                \
        __builtin_amdgcn_s_barrier();                                              \
        asm volatile("s_waitcnt lgkmcnt(0)" ::: "memory");                         \
        __builtin_amdgcn_sched_barrier(0);                                         \
        __builtin_amdgcn_s_setprio(1);                                             \
        _Pragma("unroll") for (int i_ = 0; i_ < 4; ++i_)                           \
            _Pragma("unroll") for (int s_ = 0; s_ < 2; ++s_)                       \
                _Pragma("unroll") for (int n_ = 0; n_ < 2; ++n_)                   \
                    acc[4 * (j) + i_][n_] = __builtin_amdgcn_mfma_f32_16x16x32_bf16( \
                        af[i_][s_], BRC[n_][s_], acc[4 * (j) + i_][n_], 0, 0, 0);  \
        __builtin_amdgcn_s_setprio(0);                                             \
        __builtin_amdgcn_s_barrier();                                              \
    }

    // ---- steady tiles 0..13 (pairs for breg ping-pong)
    for (int t0 = 0; t0 < 14; t0 += 2) {
        PH(0, 0, 1, br0, br1, 1, 1, 1, 6, t0)
        PH(1, 0, 1, br0, br1, 1, 1, 1, 6, t0)
        PH(2, 0, 1, br0, br1, 1, 1, 1, 6, t0)
        PH(3, 0, 1, br0, br1, 1, 1, 1, 6, t0)
        PH(0, 1, 0, br1, br0, 1, 1, 1, 6, t0 + 1)
        PH(1, 1, 0, br1, br0, 1, 1, 1, 6, t0 + 1)
        PH(2, 1, 0, br1, br0, 1, 1, 1, 6, t0 + 1)
        PH(3, 1, 0, br1, br0, 1, 1, 1, 6, t0 + 1)
    }
    // ---- tile 14: stage A-of-15 only; read B-regs for 15
    PH(0, 0, 1, br0, br1, 1, 0, 1, 5, 14)
    PH(1, 0, 1, br0, br1, 1, 0, 1, 4, 14)
    PH(2, 0, 1, br0, br1, 1, 0, 1, 3, 14)
    PH(3, 0, 1, br0, br1, 1, 0, 1, 3, 14)
    // ---- tile 15: compute only, drain
    PH(0, 1, 0, br1, br0, 0, 0, 0, 2, 15)
    PH(1, 1, 0, br1, br0, 0, 0, 0, 1, 15)
    PH(2, 1, 0, br1, br0, 0, 0, 0, 0, 15)
    PH(3, 1, 0, br1, br0, 0, 0, 0, 0, 15)
#undef PH
#undef STA
#undef STB

    // ---- epilogue: scatter to Q/K/V (B,H,L,dk) bf16
#pragma unroll
    for (int m = 0; m < 16; ++m) {
        const int mrow0 = row0 + m * 16 + lk * 4;
#pragma unroll
        for (int n = 0; n < 2; ++n) {
            const int gcol = col0 + 32 * w + 16 * n + lr;
            const int three = gcol >> 10;
            const int h = (gcol >> 6) & (NH - 1);
            const int d = gcol & (DKH - 1);
            unsigned short* dst = (three == 0) ? Qb : ((three == 1) ? Kb : Vb);
#pragma unroll
            for (int j = 0; j < 4; ++j) {
                const int mr = mrow0 + j;
                const int b = mr >> 12;
                const int t = mr & (NL - 1);
                dst[(((size_t)b * NH + h) * NL + t) * DKH + d] = f2bf(acc[m][n][j]);
            }
        }
    }
}

// ====== output GEMM (R4 128x128 m97-structure, proven 899 TF) ======
__global__ __launch_bounds__(256)
void k_gemm_out_bf16(const unsigned short* __restrict__ A, const unsigned short* __restrict__ Bm,
                     float* __restrict__ C)
{
    __shared__ short As[128 * 64];
    __shared__ short Bs[128 * 64];
    const int tid = threadIdx.x;
    const int w = tid >> 6, lane = tid & 63;
    const int wr = w >> 1, wc = w & 1;
    const int lr = lane & 15, lk = lane >> 4;

    const int nbx = gridDim.x;
    const int nwg = nbx * gridDim.y;
    const int bid = blockIdx.y * nbx + blockIdx.x;
    const int sb  = (bid & 7) * (nwg >> 3) + (bid >> 3);
    const int row0 = (sb / nbx) * 128, col0 = (sb % nbx) * 128;

    const int srow = tid >> 3;
    const int schk = (tid & 7) ^ (srow & 7);
    const unsigned short* gA = A + (size_t)(row0 + srow) * KD + schk * 8;
    const unsigned short* gB = Bm + (size_t)(col0 + srow) * KD + schk * 8;
    short* lA = As + (w * 8) * 64;
    short* lB = Bs + (w * 8) * 64;

    f32x4 acc[4][4];
#pragma unroll
    for (int m = 0; m < 4; ++m)
#pragma unroll
        for (int n = 0; n < 4; ++n) acc[m][n] = (f32x4){0.f, 0.f, 0.f, 0.f};

    int arow[4], brow[4];
#pragma unroll
    for (int m = 0; m < 4; ++m) arow[m] = (wr * 64 + m * 16 + lr) * 64;
#pragma unroll
    for (int n = 0; n < 4; ++n) brow[n] = (wc * 64 + n * 16 + lr) * 64;
    const int xr = lr & 7;
    const int coff0 = ((0 * 4 + lk) ^ xr) * 8;
    const int coff1 = ((1 * 4 + lk) ^ xr) * 8;

    for (int k0 = 0; k0 < KD; k0 += 64) {
#pragma unroll
        for (int i = 0; i < 4; ++i) gload16(gA + (size_t)(i * 32) * KD + k0, lA + i * 2048);
#pragma unroll
        for (int i = 0; i < 4; ++i) gload16(gB + (size_t)(i * 32) * KD + k0, lB + i * 2048);
        __syncthreads();
#pragma unroll
        for (int kk = 0; kk < 2; ++kk) {
            const int co = kk ? coff1 : coff0;
            bf16x8 a[4], b[4];
#pragma unroll
            for (int m = 0; m < 4; ++m) a[m] = *(const bf16x8*)(As + arow[m] + co);
#pragma unroll
            for (int n = 0; n < 4; ++n) b[n] = *(const bf16x8*)(Bs + brow[n] + co);
#pragma unroll
            for (int m = 0; m < 4; ++m)
#pragma unroll
                for (int n = 0; n < 4; ++n)
                    acc[m][n] = __builtin_amdgcn_mfma_f32_16x16x32_bf16(a[m], b[n], acc[m][n], 0, 0, 0);
        }
        __syncthreads();
    }

#pragma unroll
    for (int m = 0; m < 4; ++m) {
        const int mrow0 = row0 + wr * 64 + m * 16 + lk * 4;
#pragma unroll
        for (int n = 0; n < 4; ++n) {
            const int gcol = col0 + wc * 64 + n * 16 + lr;
#pragma unroll
            for (int j = 0; j < 4; ++j)
                C[(size_t)(mrow0 + j) * ND + gcol] = acc[m][n][j];
        }
    }
}

// ====== per-chunk local state (LN fused): SL[d][e] = sum_s g^{63-s} v_s[d] ln(k_s)[e] ======
__global__ __launch_bounds__(256)
void k_chunk_state(const unsigned short* __restrict__ Kb, const unsigned short* __restrict__ Vb,
                   const float* __restrict__ lg, unsigned short* __restrict__ SL)
{
    __shared__ unsigned short Kt[64 * 64];
    __shared__ unsigned short Vt[64 * 64];
    __shared__ float red[64][8];
    const int blk = blockIdx.x;
    const int c   = blk & (NCH - 1);
    const int bh  = blk >> 6;
    const int h   = bh & (NH - 1);
    const float gamma = dsigmoid(lg[h]);
    const float l2g = log2f(gamma);
    const int tid = threadIdx.x;
    const unsigned short* Kc = Kb + ((size_t)bh * NL + c * CK) * DKH;
    const unsigned short* Vc = Vb + ((size_t)bh * NL + c * CK) * DKH;

    const int r  = tid & 63;
    const int w4 = tid >> 6;
    const int c0 = w4 * 8;
    bf16x8 k8a = *(const bf16x8*)(Kc + (size_t)r * DKH + c0);
    bf16x8 k8b = *(const bf16x8*)(Kc + (size_t)r * DKH + c0 + 32);
    bf16x8 v8a = *(const bf16x8*)(Vc + (size_t)r * DKH + c0);
    bf16x8 v8b = *(const bf16x8*)(Vc + (size_t)r * DKH + c0 + 32);
    float sum = 0.f, sq = 0.f;
#pragma unroll
    for (int j = 0; j < 8; ++j) {
        float xa = bf2f((unsigned short)k8a[j]); sum += xa; sq += xa * xa;
        float xb = bf2f((unsigned short)k8b[j]); sum += xb; sq += xb * xb;
    }
    red[r][w4] = sum; red[r][w4 + 4] = sq;
    __syncthreads();
    float s  = red[r][0] + red[r][1] + red[r][2] + red[r][3];
    float qq = red[r][4] + red[r][5] + red[r][6] + red[r][7];
    float mu = s * (1.0f / 64.0f);
    float rstd = rsqrtf(qq * (1.0f / 64.0f) - mu * mu + 1e-5f);
    float wgt = exp2f((float)(CK - 1 - r) * l2g);
#pragma unroll
    for (int j = 0; j < 8; ++j) {
        Kt[swz(c0 + j, r)]      = f2bf((bf2f((unsigned short)k8a[j]) - mu) * rstd);
        Kt[swz(c0 + 32 + j, r)] = f2bf((bf2f((unsigned short)k8b[j]) - mu) * rstd);
        Vt[swz(c0 + j, r)]      = f2bf(bf2f((unsigned short)v8a[j]) * wgt);
        Vt[swz(c0 + 32 + j, r)] = f2bf(bf2f((unsigned short)v8b[j]) * wgt);
    }
    __syncthreads();

    const int w = tid >> 6, lane = tid & 63;
    const int wr = w >> 1, wc = w & 1;
    const int lr = lane & 15, lk = lane >> 4;
    f32x4 acc[2][2];
#pragma unroll
    for (int m = 0; m < 2; ++m)
#pragma unroll
        for (int n = 0; n < 2; ++n) acc[m][n] = (f32x4){0.f, 0.f, 0.f, 0.f};
#pragma unroll
    for (int kk = 0; kk < 2; ++kk) {
        const int so = kk * 32 + lk * 8;
        bf16x8 a[2], b[2];
#pragma unroll
        for (int m = 0; m < 2; ++m) a[m] = *(const bf16x8*)&Vt[swz(wr * 32 + m * 16 + lr, so)];
#pragma unroll
        for (int n = 0; n < 2; ++n) b[n] = *(const bf16x8*)&Kt[swz(wc * 32 + n * 16 + lr, so)];
#pragma unroll
        for (int m = 0; m < 2; ++m)
#pragma unroll
            for (int n = 0; n < 2; ++n)
                acc[m][n] = __builtin_amdgcn_mfma_f32_16x16x32_bf16(a[m], b[n], acc[m][n], 0, 0, 0);
    }

    unsigned short* out = SL + (size_t)blk * (DKH * DKH);
#pragma unroll
    for (int m = 0; m < 2; ++m)
#pragma unroll
        for (int n = 0; n < 2; ++n)
#pragma unroll
            for (int j = 0; j < 4; ++j) {
                int d = wr * 32 + m * 16 + lk * 4 + j;
                int e = wc * 32 + n * 16 + lr;
                out[d * DKH + e] = f2bf(acc[m][n][j]);
            }
}

// ====== sequential scan over chunks: SS[c] = state BEFORE chunk c ======
__global__ __launch_bounds__(256)
void k_scan(const unsigned short* __restrict__ SL, const float* __restrict__ lg,
            unsigned short* __restrict__ SS)
{
    const int bh = blockIdx.x;
    const int qt = blockIdx.y;
    const int h  = bh & (NH - 1);
    const float gamma = dsigmoid(lg[h]);
    const float dc = __powf(gamma, (float)CK);
    const size_t base = (size_t)bh * NCH * (DKH * DKH) + qt * 1024 + threadIdx.x * 4;
    float s0 = 0.f, s1 = 0.f, s2 = 0.f, s3 = 0.f;
    for (int c = 0; c < NCH; ++c) {
        const size_t off = base + (size_t)c * (DKH * DKH);
        ushort4 l = *(const ushort4*)(SL + off);
        ushort4 o;
        o.x = f2bf(s0); o.y = f2bf(s1); o.z = f2bf(s2); o.w = f2bf(s3);
        *(ushort4*)(SS + off) = o;
        s0 = s0 * dc + bf2f(l.x); s1 = s1 * dc + bf2f(l.y);
        s2 = s2 * dc + bf2f(l.z); s3 = s3 * dc + bf2f(l.w);
    }
}

// ====== per-chunk output (LN fused): Y = mask(Q K^T)V + g^{t+1} Q S^T, coalesced bf16 out ======
__global__ __launch_bounds__(256)
void k_chunk_out(const unsigned short* __restrict__ Qb, const unsigned short* __restrict__ Kb,
                 const unsigned short* __restrict__ Vb, const unsigned short* __restrict__ SS,
                 const float* __restrict__ lg, unsigned short* __restrict__ Y)
{
    __shared__ unsigned short Qs[64 * 64];
    __shared__ unsigned short Ks[64 * 64];
    __shared__ unsigned short Vt[64 * 64];
    __shared__ unsigned short Ss[64 * 64];
    __shared__ unsigned short Ps[64 * 64];
    __shared__ float red[64][8];
    const int blk = blockIdx.x;
    const int c   = blk & (NCH - 1);
    const int bh  = blk >> 6;
    const int h   = bh & (NH - 1);
    const int b   = bh >> 4;
    const float gamma = dsigmoid(lg[h]);
    const float l2g = log2f(gamma);
    const int tid = threadIdx.x;
    const unsigned short* Qc = Qb + ((size_t)bh * NL + c * CK) * DKH;
    const unsigned short* Kc = Kb + ((size_t)bh * NL + c * CK) * DKH;
    const unsigned short* Vc = Vb + ((size_t)bh * NL + c * CK) * DKH;
    const unsigned short* Sc = SS + (size_t)blk * (DKH * DKH);

    const int r  = tid & 63;
    const int w4 = tid >> 6;
    const int c0 = w4 * 8;
    bf16x8 q8a = *(const bf16x8*)(Qc + (size_t)r * DKH + c0);
    bf16x8 q8b = *(const bf16x8*)(Qc + (size_t)r * DKH + c0 + 32);
    bf16x8 k8a = *(const bf16x8*)(Kc + (size_t)r * DKH + c0);
    bf16x8 k8b = *(const bf16x8*)(Kc + (size_t)r * DKH + c0 + 32);
    bf16x8 v8a = *(const bf16x8*)(Vc + (size_t)r * DKH + c0);
    bf16x8 v8b = *(const bf16x8*)(Vc + (size_t)r * DKH + c0 + 32);
    bf16x8 s8a = *(const bf16x8*)(Sc + (size_t)r * DKH + c0);
    bf16x8 s8b = *(const bf16x8*)(Sc + (size_t)r * DKH + c0 + 32);
    float sum = 0.f, sq = 0.f;
#pragma unroll
    for (int j = 0; j < 8; ++j) {
        float xa = bf2f((unsigned short)k8a[j]); sum += xa; sq += xa * xa;
        float xb = bf2f((unsigned short)k8b[j]); sum += xb; sq += xb * xb;
    }
    red[r][w4] = sum; red[r][w4 + 4] = sq;
    __syncthreads();
    float sm = red[r][0] + red[r][1] + red[r][2] + red[r][3];
    float qq = red[r][4] + red[r][5] + red[r][6] + red[r][7];
    float mu = sm * (1.0f / 64.0f);
    float rstd = rsqrtf(qq * (1.0f / 64.0f) - mu * mu + 1e-5f);
    *(bf16x8*)&Qs[swz(r, c0)]      = q8a;
    *(bf16x8*)&Qs[swz(r, c0 + 32)] = q8b;
    *(bf16x8*)&Ss[swz(r, c0)]      = s8a;
    *(bf16x8*)&Ss[swz(r, c0 + 32)] = s8b;
#pragma unroll
    for (int j = 0; j < 8; ++j) {
        Ks[swz(r, c0 + j)]      = f2bf((bf2f((unsigned short)k8a[j]) - mu) * rstd);
        Ks[swz(r, c0 + 32 + j)] = f2bf((bf2f((unsigned short)k8b[j]) - mu) * rstd);
        Vt[swz(c0 + j, r)]      = (unsigned short)v8a[j];
        Vt[swz(c0 + 32 + j, r)] = (unsigned short)v8b[j];
    }
    __syncthreads();

    const int w = tid >> 6, lane = tid & 63;
    const int wr = w >> 1, wc = w & 1;
    const int lr = lane & 15, lk = lane >> 4;

    f32x4 accp[2][2];
#pragma unroll
    for (int m = 0; m < 2; ++m)
#pragma unroll
        for (int n = 0; n < 2; ++n) accp[m][n] = (f32x4){0.f, 0.f, 0.f, 0.f};
#pragma unroll
    for (int kk = 0; kk < 2; ++kk) {
        const int eo = kk * 32 + lk * 8;
        bf16x8 a[2], bfr[2];
#pragma unroll
        for (int m = 0; m < 2; ++m) a[m]   = *(const bf16x8*)&Qs[swz(wr * 32 + m * 16 + lr, eo)];
#pragma unroll
        for (int n = 0; n < 2; ++n) bfr[n] = *(const bf16x8*)&Ks[swz(wc * 32 + n * 16 + lr, eo)];
#pragma unroll
        for (int m = 0; m < 2; ++m)
#pragma unroll
            for (int n = 0; n < 2; ++n)
                accp[m][n] = __builtin_amdgcn_mfma_f32_16x16x32_bf16(a[m], bfr[n], accp[m][n], 0, 0, 0);
    }
#pragma unroll
    for (int m = 0; m < 2; ++m)
#pragma unroll
        for (int n = 0; n < 2; ++n)
#pragma unroll
            for (int j = 0; j < 4; ++j) {
                int t = wr * 32 + m * 16 + lk * 4 + j;
                int s = wc * 32 + n * 16 + lr;
                int dt = t - s;
                float v = (dt >= 0) ? accp[m][n][j] * exp2f((float)dt * l2g) : 0.0f;
                Ps[swz(t, s)] = f2bf(v);
            }
    __syncthreads();

    f32x4 accy[2][2], accz[2][2];
#pragma unroll
    for (int m = 0; m < 2; ++m)
#pragma unroll
        for (int n = 0; n < 2; ++n) {
            accy[m][n] = (f32x4){0.f, 0.f, 0.f, 0.f};
            accz[m][n] = (f32x4){0.f, 0.f, 0.f, 0.f};
        }
#pragma unroll
    for (int kk = 0; kk < 2; ++kk) {
        const int so = kk * 32 + lk * 8;
        bf16x8 pa[2], qa[2], vb[2], sb[2];
#pragma unroll
        for (int m = 0; m < 2; ++m) {
            pa[m] = *(const bf16x8*)&Ps[swz(wr * 32 + m * 16 + lr, so)];
            qa[m] = *(const bf16x8*)&Qs[swz(wr * 32 + m * 16 + lr, so)];
        }
#pragma unroll
        for (int n = 0; n < 2; ++n) {
            vb[n] = *(const bf16x8*)&Vt[swz(wc * 32 + n * 16 + lr, so)];
            sb[n] = *(const bf16x8*)&Ss[swz(wc * 32 + n * 16 + lr, so)];
        }
#pragma unroll
        for (int m = 0; m < 2; ++m)
#pragma unroll
            for (int n = 0; n < 2; ++n) {
                accy[m][n] = __builtin_amdgcn_mfma_f32_16x16x32_bf16(pa[m], vb[n], accy[m][n], 0, 0, 0);
                accz[m][n] = __builtin_amdgcn_mfma_f32_16x16x32_bf16(qa[m], sb[n], accz[m][n], 0, 0, 0);
            }
    }
    __syncthreads();

#pragma unroll
    for (int m = 0; m < 2; ++m)
#pragma unroll
        for (int n = 0; n < 2; ++n)
#pragma unroll
            for (int j = 0; j < 4; ++j) {
                int t = wr * 32 + m * 16 + lk * 4 + j;
                int d = wc * 32 + n * 16 + lr;
                float g = exp2f((float)(t + 1) * l2g);
                Ps[swz(t, d)] = f2bf(accy[m][n][j] + g * accz[m][n][j]);
            }
    __syncthreads();

#pragma unroll
    for (int i = 0; i < 2; ++i) {
        int f  = tid + i * 256;
        int rr = f >> 3;
        int ch = f & 7;
        bf16x8 val = *(const bf16x8*)&Ps[swz(rr, ch * 8)];
        unsigned short* p = Y + ((size_t)(b * NL + c * CK + rr)) * ND + h * DKH + ch * 8;
        *(bf16x8*)p = val;
    }
}

extern "C" void kernel_launch(void* const* d_in, const int* in_sizes, int n_in,
                              void* d_out, int out_size, void* d_ws, size_t ws_size,
                              hipStream_t stream)
{
    (void)in_sizes; (void)n_in; (void)out_size; (void)ws_size;
    const float* x  = (const float*)d_in[0];
    const float* Wq = (const float*)d_in[1];
    const float* Wo = (const float*)d_in[2];
    const float* lg = (const float*)d_in[3];
    float* out = (float*)d_out;

    const size_t SZ = (size_t)NB * NH * NL * DKH;
    unsigned short* xb  = (unsigned short*)d_ws;
    unsigned short* Wqb = xb + SZ;
    unsigned short* Wob = Wqb + (size_t)3 * ND * ND;
    unsigned short* Qb  = Wob + (size_t)ND * ND;
    unsigned short* Kb  = Qb + SZ;
    unsigned short* Vb  = Kb + SZ;
    unsigned short* SL  = Vb + SZ;
    unsigned short* SS  = SL + SZ;
    unsigned short* Ybb = SS + SZ;

    k_cast_all<<<2048, 256, 0, stream>>>(x, Wq, Wo, xb, Wqb, Wob);
    k_gemm_qkv_8p<<<dim3(3 * ND / 256, NM / 256), 512, 0, stream>>>(xb, Wqb, Qb, Kb, Vb);
    k_chunk_state<<<dim3(NB * NH * NCH), 256, 0, stream>>>(Kb, Vb, lg, SL);
    k_scan<<<dim3(NB * NH, 4), 256, 0, stream>>>(SL, lg, SS);
    k_chunk_out<<<dim3(NB * NH * NCH), 256, 0, stream>>>(Qb, Kb, Vb, SS, lg, Ybb);
    k_gemm_out_bf16<<<dim3(ND / 128, NM / 128), 256, 0, stream>>>(Ybb, Wob, out);
}

// Round 7
// 135.267 us; speedup vs baseline: 1.1146x; 1.0651x over previous
//
#include <hip/hip_runtime.h>
#include <cstddef>

// RetNetAttention round 7: revert qkv to proven R4 128x128 m97-structure GEMM
// (899 TF); scan occupancy fix (512 one-wave blocks). Rest identical to R4.
#define NB 2
#define NL 4096
#define ND 1024
#define NH 16
#define DKH 64
#define CK 64
#define NCH (NL / CK)
#define NM (NB * NL)
#define KD 1024

typedef __attribute__((ext_vector_type(8))) short bf16x8;
typedef __attribute__((ext_vector_type(4))) float f32x4;

__device__ __forceinline__ float dsigmoid(float x) { return 1.0f / (1.0f + __expf(-x)); }
__device__ __forceinline__ float bf2f(unsigned short u) { return __uint_as_float((unsigned)u << 16); }
__device__ __forceinline__ unsigned short f2bf(float f) {
    unsigned u = __float_as_uint(f);
    u = (u + 0x7fffu + ((u >> 16) & 1u)) >> 16;
    return (unsigned short)u;
}
// element index into [R][64]-ushort tile, XOR-swizzled at 8-elem (16B) granularity
__device__ __forceinline__ int swz(int row, int col) { return row * 64 + (col ^ ((row & 7) << 3)); }

__device__ __forceinline__ void gload16(const void* g, void* l) {
    __builtin_amdgcn_global_load_lds(
        (const __attribute__((address_space(1))) unsigned int*)g,
        (__attribute__((address_space(3))) unsigned int*)l, 16, 0, 0);
}

// ================= fused fp32 -> bf16 casts =================
__global__ __launch_bounds__(256)
void k_cast_all(const float* __restrict__ x, const float* __restrict__ Wq,
                const float* __restrict__ Wo, unsigned short* __restrict__ xb,
                unsigned short* __restrict__ Wqb, unsigned short* __restrict__ Wob)
{
    const int N1 = NB * NL * ND / 4;
    const int N2 = 3 * ND * ND / 4;
    const int N3 = ND * ND / 4;
    const int total = N1 + N2 + N3;
    int i = blockIdx.x * 256 + threadIdx.x;
    const int stride = gridDim.x * 256;
    for (; i < total; i += stride) {
        const float4* src;
        ushort4* dst;
        int j;
        if (i < N1)            { src = (const float4*)x;  dst = (ushort4*)xb;  j = i; }
        else if (i < N1 + N2)  { src = (const float4*)Wq; dst = (ushort4*)Wqb; j = i - N1; }
        else                   { src = (const float4*)Wo; dst = (ushort4*)Wob; j = i - N1 - N2; }
        float4 v = src[j];
        ushort4 o;
        o.x = f2bf(v.x); o.y = f2bf(v.y); o.z = f2bf(v.z); o.w = f2bf(v.w);
        dst[j] = o;
    }
}

// ====== bf16 MFMA GEMM (NT), 128x128 tile, BK=64, swizzled LDS reads (R4, 899 TF) ======
__global__ __launch_bounds__(256)
void k_gemm_qkv_bf16(const unsigned short* __restrict__ A, const unsigned short* __restrict__ Bm,
                     unsigned short* __restrict__ Qb, unsigned short* __restrict__ Kb,
                     unsigned short* __restrict__ Vb)
{
    __shared__ short As[128 * 64];
    __shared__ short Bs[128 * 64];
    const int tid = threadIdx.x;
    const int w = tid >> 6, lane = tid & 63;
    const int wr = w >> 1, wc = w & 1;
    const int lr = lane & 15, lk = lane >> 4;

    // T1 bijective XCD swizzle (nwg % 8 == 0)
    const int nbx = gridDim.x;
    const int nwg = nbx * gridDim.y;
    const int bid = blockIdx.y * nbx + blockIdx.x;
    const int sb  = (bid & 7) * (nwg >> 3) + (bid >> 3);
    const int row0 = (sb / nbx) * 128, col0 = (sb % nbx) * 128;

    const int srow = tid >> 3;                         // 0..31
    const int schk = (tid & 7) ^ (srow & 7);           // pre-swizzled source chunk
    const unsigned short* gA = A + (size_t)(row0 + srow) * KD + schk * 8;
    const unsigned short* gB = Bm + (size_t)(col0 + srow) * KD + schk * 8;
    short* lA = As + (w * 8) * 64;
    short* lB = Bs + (w * 8) * 64;

    f32x4 acc[4][4];
#pragma unroll
    for (int m = 0; m < 4; ++m)
#pragma unroll
        for (int n = 0; n < 4; ++n) acc[m][n] = (f32x4){0.f, 0.f, 0.f, 0.f};

    int arow[4], brow[4];
#pragma unroll
    for (int m = 0; m < 4; ++m) arow[m] = (wr * 64 + m * 16 + lr) * 64;
#pragma unroll
    for (int n = 0; n < 4; ++n) brow[n] = (wc * 64 + n * 16 + lr) * 64;
    const int xr = lr & 7;
    const int coff0 = ((0 * 4 + lk) ^ xr) * 8;
    const int coff1 = ((1 * 4 + lk) ^ xr) * 8;

    for (int k0 = 0; k0 < KD; k0 += 64) {
#pragma unroll
        for (int i = 0; i < 4; ++i) gload16(gA + (size_t)(i * 32) * KD + k0, lA + i * 2048);
#pragma unroll
        for (int i = 0; i < 4; ++i) gload16(gB + (size_t)(i * 32) * KD + k0, lB + i * 2048);
        __syncthreads();
#pragma unroll
        for (int kk = 0; kk < 2; ++kk) {
            const int co = kk ? coff1 : coff0;
            bf16x8 a[4], b[4];
#pragma unroll
            for (int m = 0; m < 4; ++m) a[m] = *(const bf16x8*)(As + arow[m] + co);
#pragma unroll
            for (int n = 0; n < 4; ++n) b[n] = *(const bf16x8*)(Bs + brow[n] + co);
#pragma unroll
            for (int m = 0; m < 4; ++m)
#pragma unroll
                for (int n = 0; n < 4; ++n)
                    acc[m][n] = __builtin_amdgcn_mfma_f32_16x16x32_bf16(a[m], b[n], acc[m][n], 0, 0, 0);
        }
        __syncthreads();
    }

#pragma unroll
    for (int m = 0; m < 4; ++m) {
        const int mrow0 = row0 + wr * 64 + m * 16 + lk * 4;
#pragma unroll
        for (int n = 0; n < 4; ++n) {
            const int gcol = col0 + wc * 64 + n * 16 + lr;
            const int three = gcol >> 10;
            const int h = (gcol >> 6) & (NH - 1);
            const int d = gcol & (DKH - 1);
            unsigned short* dst = (three == 0) ? Qb : ((three == 1) ? Kb : Vb);
#pragma unroll
            for (int j = 0; j < 4; ++j) {
                const int mr = mrow0 + j;
                const int b = mr >> 12;
                const int t = mr & (NL - 1);
                dst[(((size_t)b * NH + h) * NL + t) * DKH + d] = f2bf(acc[m][n][j]);
            }
        }
    }
}

__global__ __launch_bounds__(256)
void k_gemm_out_bf16(const unsigned short* __restrict__ A, const unsigned short* __restrict__ Bm,
                     float* __restrict__ C)
{
    __shared__ short As[128 * 64];
    __shared__ short Bs[128 * 64];
    const int tid = threadIdx.x;
    const int w = tid >> 6, lane = tid & 63;
    const int wr = w >> 1, wc = w & 1;
    const int lr = lane & 15, lk = lane >> 4;

    const int nbx = gridDim.x;
    const int nwg = nbx * gridDim.y;
    const int bid = blockIdx.y * nbx + blockIdx.x;
    const int sb  = (bid & 7) * (nwg >> 3) + (bid >> 3);
    const int row0 = (sb / nbx) * 128, col0 = (sb % nbx) * 128;

    const int srow = tid >> 3;
    const int schk = (tid & 7) ^ (srow & 7);
    const unsigned short* gA = A + (size_t)(row0 + srow) * KD + schk * 8;
    const unsigned short* gB = Bm + (size_t)(col0 + srow) * KD + schk * 8;
    short* lA = As + (w * 8) * 64;
    short* lB = Bs + (w * 8) * 64;

    f32x4 acc[4][4];
#pragma unroll
    for (int m = 0; m < 4; ++m)
#pragma unroll
        for (int n = 0; n < 4; ++n) acc[m][n] = (f32x4){0.f, 0.f, 0.f, 0.f};

    int arow[4], brow[4];
#pragma unroll
    for (int m = 0; m < 4; ++m) arow[m] = (wr * 64 + m * 16 + lr) * 64;
#pragma unroll
    for (int n = 0; n < 4; ++n) brow[n] = (wc * 64 + n * 16 + lr) * 64;
    const int xr = lr & 7;
    const int coff0 = ((0 * 4 + lk) ^ xr) * 8;
    const int coff1 = ((1 * 4 + lk) ^ xr) * 8;

    for (int k0 = 0; k0 < KD; k0 += 64) {
#pragma unroll
        for (int i = 0; i < 4; ++i) gload16(gA + (size_t)(i * 32) * KD + k0, lA + i * 2048);
#pragma unroll
        for (int i = 0; i < 4; ++i) gload16(gB + (size_t)(i * 32) * KD + k0, lB + i * 2048);
        __syncthreads();
#pragma unroll
        for (int kk = 0; kk < 2; ++kk) {
            const int co = kk ? coff1 : coff0;
            bf16x8 a[4], b[4];
#pragma unroll
            for (int m = 0; m < 4; ++m) a[m] = *(const bf16x8*)(As + arow[m] + co);
#pragma unroll
            for (int n = 0; n < 4; ++n) b[n] = *(const bf16x8*)(Bs + brow[n] + co);
#pragma unroll
            for (int m = 0; m < 4; ++m)
#pragma unroll
                for (int n = 0; n < 4; ++n)
                    acc[m][n] = __builtin_amdgcn_mfma_f32_16x16x32_bf16(a[m], b[n], acc[m][n], 0, 0, 0);
        }
        __syncthreads();
    }

#pragma unroll
    for (int m = 0; m < 4; ++m) {
        const int mrow0 = row0 + wr * 64 + m * 16 + lk * 4;
#pragma unroll
        for (int n = 0; n < 4; ++n) {
            const int gcol = col0 + wc * 64 + n * 16 + lr;
#pragma unroll
            for (int j = 0; j < 4; ++j)
                C[(size_t)(mrow0 + j) * ND + gcol] = acc[m][n][j];
        }
    }
}

// ====== per-chunk local state (LN fused): SL[d][e] = sum_s g^{63-s} v_s[d] ln(k_s)[e] ======
__global__ __launch_bounds__(256)
void k_chunk_state(const unsigned short* __restrict__ Kb, const unsigned short* __restrict__ Vb,
                   const float* __restrict__ lg, unsigned short* __restrict__ SL)
{
    __shared__ unsigned short Kt[64 * 64];
    __shared__ unsigned short Vt[64 * 64];
    __shared__ float red[64][8];
    const int blk = blockIdx.x;
    const int c   = blk & (NCH - 1);
    const int bh  = blk >> 6;
    const int h   = bh & (NH - 1);
    const float gamma = dsigmoid(lg[h]);
    const float l2g = log2f(gamma);
    const int tid = threadIdx.x;
    const unsigned short* Kc = Kb + ((size_t)bh * NL + c * CK) * DKH;
    const unsigned short* Vc = Vb + ((size_t)bh * NL + c * CK) * DKH;

    const int r  = tid & 63;
    const int w4 = tid >> 6;
    const int c0 = w4 * 8;
    bf16x8 k8a = *(const bf16x8*)(Kc + (size_t)r * DKH + c0);
    bf16x8 k8b = *(const bf16x8*)(Kc + (size_t)r * DKH + c0 + 32);
    bf16x8 v8a = *(const bf16x8*)(Vc + (size_t)r * DKH + c0);
    bf16x8 v8b = *(const bf16x8*)(Vc + (size_t)r * DKH + c0 + 32);
    float sum = 0.f, sq = 0.f;
#pragma unroll
    for (int j = 0; j < 8; ++j) {
        float xa = bf2f((unsigned short)k8a[j]); sum += xa; sq += xa * xa;
        float xb = bf2f((unsigned short)k8b[j]); sum += xb; sq += xb * xb;
    }
    red[r][w4] = sum; red[r][w4 + 4] = sq;
    __syncthreads();
    float s  = red[r][0] + red[r][1] + red[r][2] + red[r][3];
    float qq = red[r][4] + red[r][5] + red[r][6] + red[r][7];
    float mu = s * (1.0f / 64.0f);
    float rstd = rsqrtf(qq * (1.0f / 64.0f) - mu * mu + 1e-5f);
    float wgt = exp2f((float)(CK - 1 - r) * l2g);
#pragma unroll
    for (int j = 0; j < 8; ++j) {
        Kt[swz(c0 + j, r)]      = f2bf((bf2f((unsigned short)k8a[j]) - mu) * rstd);
        Kt[swz(c0 + 32 + j, r)] = f2bf((bf2f((unsigned short)k8b[j]) - mu) * rstd);
        Vt[swz(c0 + j, r)]      = f2bf(bf2f((unsigned short)v8a[j]) * wgt);
        Vt[swz(c0 + 32 + j, r)] = f2bf(bf2f((unsigned short)v8b[j]) * wgt);
    }
    __syncthreads();

    const int w = tid >> 6, lane = tid & 63;
    const int wr = w >> 1, wc = w & 1;
    const int lr = lane & 15, lk = lane >> 4;
    f32x4 acc[2][2];
#pragma unroll
    for (int m = 0; m < 2; ++m)
#pragma unroll
        for (int n = 0; n < 2; ++n) acc[m][n] = (f32x4){0.f, 0.f, 0.f, 0.f};
#pragma unroll
    for (int kk = 0; kk < 2; ++kk) {
        const int so = kk * 32 + lk * 8;
        bf16x8 a[2], b[2];
#pragma unroll
        for (int m = 0; m < 2; ++m) a[m] = *(const bf16x8*)&Vt[swz(wr * 32 + m * 16 + lr, so)];
#pragma unroll
        for (int n = 0; n < 2; ++n) b[n] = *(const bf16x8*)&Kt[swz(wc * 32 + n * 16 + lr, so)];
#pragma unroll
        for (int m = 0; m < 2; ++m)
#pragma unroll
            for (int n = 0; n < 2; ++n)
                acc[m][n] = __builtin_amdgcn_mfma_f32_16x16x32_bf16(a[m], b[n], acc[m][n], 0, 0, 0);
    }

    unsigned short* out = SL + (size_t)blk * (DKH * DKH);
#pragma unroll
    for (int m = 0; m < 2; ++m)
#pragma unroll
        for (int n = 0; n < 2; ++n)
#pragma unroll
            for (int j = 0; j < 4; ++j) {
                int d = wr * 32 + m * 16 + lk * 4 + j;
                int e = wc * 32 + n * 16 + lr;
                out[d * DKH + e] = f2bf(acc[m][n][j]);
            }
}

// ====== sequential scan over chunks: SS[c] = state BEFORE chunk c ======
// 512 one-wave blocks (32 bh x 16 slices of the 64x64 state) for full-chip occupancy.
__global__ __launch_bounds__(64)
void k_scan(const unsigned short* __restrict__ SL, const float* __restrict__ lg,
            unsigned short* __restrict__ SS)
{
    const int bh = blockIdx.x;
    const int qt = blockIdx.y;                 // 0..15
    const int h  = bh & (NH - 1);
    const float gamma = dsigmoid(lg[h]);
    const float dc = __powf(gamma, (float)CK);
    const size_t base = (size_t)bh * NCH * (DKH * DKH) + qt * 256 + threadIdx.x * 4;
    float s0 = 0.f, s1 = 0.f, s2 = 0.f, s3 = 0.f;
    for (int c = 0; c < NCH; ++c) {
        const size_t off = base + (size_t)c * (DKH * DKH);
        ushort4 l = *(const ushort4*)(SL + off);
        ushort4 o;
        o.x = f2bf(s0); o.y = f2bf(s1); o.z = f2bf(s2); o.w = f2bf(s3);
        *(ushort4*)(SS + off) = o;
        s0 = s0 * dc + bf2f(l.x); s1 = s1 * dc + bf2f(l.y);
        s2 = s2 * dc + bf2f(l.z); s3 = s3 * dc + bf2f(l.w);
    }
}

// ====== per-chunk output (LN fused): Y = mask(Q K^T)V + g^{t+1} Q S^T, coalesced bf16 out ======
__global__ __launch_bounds__(256)
void k_chunk_out(const unsigned short* __restrict__ Qb, const unsigned short* __restrict__ Kb,
                 const unsigned short* __restrict__ Vb, const unsigned short* __restrict__ SS,
                 const float* __restrict__ lg, unsigned short* __restrict__ Y)
{
    __shared__ unsigned short Qs[64 * 64];
    __shared__ unsigned short Ks[64 * 64];
    __shared__ unsigned short Vt[64 * 64];
    __shared__ unsigned short Ss[64 * 64];
    __shared__ unsigned short Ps[64 * 64];   // reused as Y-staging
    __shared__ float red[64][8];
    const int blk = blockIdx.x;
    const int c   = blk & (NCH - 1);
    const int bh  = blk >> 6;
    const int h   = bh & (NH - 1);
    const int b   = bh >> 4;
    const float gamma = dsigmoid(lg[h]);
    const float l2g = log2f(gamma);
    const int tid = threadIdx.x;
    const unsigned short* Qc = Qb + ((size_t)bh * NL + c * CK) * DKH;
    const unsigned short* Kc = Kb + ((size_t)bh * NL + c * CK) * DKH;
    const unsigned short* Vc = Vb + ((size_t)bh * NL + c * CK) * DKH;
    const unsigned short* Sc = SS + (size_t)blk * (DKH * DKH);

    const int r  = tid & 63;
    const int w4 = tid >> 6;
    const int c0 = w4 * 8;
    bf16x8 q8a = *(const bf16x8*)(Qc + (size_t)r * DKH + c0);
    bf16x8 q8b = *(const bf16x8*)(Qc + (size_t)r * DKH + c0 + 32);
    bf16x8 k8a = *(const bf16x8*)(Kc + (size_t)r * DKH + c0);
    bf16x8 k8b = *(const bf16x8*)(Kc + (size_t)r * DKH + c0 + 32);
    bf16x8 v8a = *(const bf16x8*)(Vc + (size_t)r * DKH + c0);
    bf16x8 v8b = *(const bf16x8*)(Vc + (size_t)r * DKH + c0 + 32);
    bf16x8 s8a = *(const bf16x8*)(Sc + (size_t)r * DKH + c0);
    bf16x8 s8b = *(const bf16x8*)(Sc + (size_t)r * DKH + c0 + 32);
    float sum = 0.f, sq = 0.f;
#pragma unroll
    for (int j = 0; j < 8; ++j) {
        float xa = bf2f((unsigned short)k8a[j]); sum += xa; sq += xa * xa;
        float xb = bf2f((unsigned short)k8b[j]); sum += xb; sq += xb * xb;
    }
    red[r][w4] = sum; red[r][w4 + 4] = sq;
    __syncthreads();
    float sm = red[r][0] + red[r][1] + red[r][2] + red[r][3];
    float qq = red[r][4] + red[r][5] + red[r][6] + red[r][7];
    float mu = sm * (1.0f / 64.0f);
    float rstd = rsqrtf(qq * (1.0f / 64.0f) - mu * mu + 1e-5f);
    *(bf16x8*)&Qs[swz(r, c0)]      = q8a;
    *(bf16x8*)&Qs[swz(r, c0 + 32)] = q8b;
    *(bf16x8*)&Ss[swz(r, c0)]      = s8a;
    *(bf16x8*)&Ss[swz(r, c0 + 32)] = s8b;
#pragma unroll
    for (int j = 0; j < 8; ++j) {
        Ks[swz(r, c0 + j)]      = f2bf((bf2f((unsigned short)k8a[j]) - mu) * rstd);
        Ks[swz(r, c0 + 32 + j)] = f2bf((bf2f((unsigned short)k8b[j]) - mu) * rstd);
        Vt[swz(c0 + j, r)]      = (unsigned short)v8a[j];
        Vt[swz(c0 + 32 + j, r)] = (unsigned short)v8b[j];
    }
    __syncthreads();

    const int w = tid >> 6, lane = tid & 63;
    const int wr = w >> 1, wc = w & 1;
    const int lr = lane & 15, lk = lane >> 4;

    // phase A: P = Q K^T with causal decay
    f32x4 accp[2][2];
#pragma unroll
    for (int m = 0; m < 2; ++m)
#pragma unroll
        for (int n = 0; n < 2; ++n) accp[m][n] = (f32x4){0.f, 0.f, 0.f, 0.f};
#pragma unroll
    for (int kk = 0; kk < 2; ++kk) {
        const int eo = kk * 32 + lk * 8;
        bf16x8 a[2], bfr[2];
#pragma unroll
        for (int m = 0; m < 2; ++m) a[m]   = *(const bf16x8*)&Qs[swz(wr * 32 + m * 16 + lr, eo)];
#pragma unroll
        for (int n = 0; n < 2; ++n) bfr[n] = *(const bf16x8*)&Ks[swz(wc * 32 + n * 16 + lr, eo)];
#pragma unroll
        for (int m = 0; m < 2; ++m)
#pragma unroll
            for (int n = 0; n < 2; ++n)
                accp[m][n] = __builtin_amdgcn_mfma_f32_16x16x32_bf16(a[m], bfr[n], accp[m][n], 0, 0, 0);
    }
#pragma unroll
    for (int m = 0; m < 2; ++m)
#pragma unroll
        for (int n = 0; n < 2; ++n)
#pragma unroll
            for (int j = 0; j < 4; ++j) {
                int t = wr * 32 + m * 16 + lk * 4 + j;
                int s = wc * 32 + n * 16 + lr;
                int dt = t - s;
                float v = (dt >= 0) ? accp[m][n][j] * exp2f((float)dt * l2g) : 0.0f;
                Ps[swz(t, s)] = f2bf(v);
            }
    __syncthreads();

    // phase B
    f32x4 accy[2][2], accz[2][2];
#pragma unroll
    for (int m = 0; m < 2; ++m)
#pragma unroll
        for (int n = 0; n < 2; ++n) {
            accy[m][n] = (f32x4){0.f, 0.f, 0.f, 0.f};
            accz[m][n] = (f32x4){0.f, 0.f, 0.f, 0.f};
        }
#pragma unroll
    for (int kk = 0; kk < 2; ++kk) {
        const int so = kk * 32 + lk * 8;
        bf16x8 pa[2], qa[2], vb[2], sb[2];
#pragma unroll
        for (int m = 0; m < 2; ++m) {
            pa[m] = *(const bf16x8*)&Ps[swz(wr * 32 + m * 16 + lr, so)];
            qa[m] = *(const bf16x8*)&Qs[swz(wr * 32 + m * 16 + lr, so)];
        }
#pragma unroll
        for (int n = 0; n < 2; ++n) {
            vb[n] = *(const bf16x8*)&Vt[swz(wc * 32 + n * 16 + lr, so)];
            sb[n] = *(const bf16x8*)&Ss[swz(wc * 32 + n * 16 + lr, so)];
        }
#pragma unroll
        for (int m = 0; m < 2; ++m)
#pragma unroll
            for (int n = 0; n < 2; ++n) {
                accy[m][n] = __builtin_amdgcn_mfma_f32_16x16x32_bf16(pa[m], vb[n], accy[m][n], 0, 0, 0);
                accz[m][n] = __builtin_amdgcn_mfma_f32_16x16x32_bf16(qa[m], sb[n], accz[m][n], 0, 0, 0);
            }
    }
    __syncthreads();   // Ps reads done; safe to overwrite as Y-staging

#pragma unroll
    for (int m = 0; m < 2; ++m)
#pragma unroll
        for (int n = 0; n < 2; ++n)
#pragma unroll
            for (int j = 0; j < 4; ++j) {
                int t = wr * 32 + m * 16 + lk * 4 + j;
                int d = wc * 32 + n * 16 + lr;
                float g = exp2f((float)(t + 1) * l2g);
                Ps[swz(t, d)] = f2bf(accy[m][n][j] + g * accz[m][n][j]);
            }
    __syncthreads();

    // coalesced write: each row = 128B contiguous
#pragma unroll
    for (int i = 0; i < 2; ++i) {
        int f  = tid + i * 256;
        int rr = f >> 3;
        int ch = f & 7;
        bf16x8 val = *(const bf16x8*)&Ps[swz(rr, ch * 8)];
        unsigned short* p = Y + ((size_t)(b * NL + c * CK + rr)) * ND + h * DKH + ch * 8;
        *(bf16x8*)p = val;
    }
}

extern "C" void kernel_launch(void* const* d_in, const int* in_sizes, int n_in,
                              void* d_out, int out_size, void* d_ws, size_t ws_size,
                              hipStream_t stream)
{
    (void)in_sizes; (void)n_in; (void)out_size; (void)ws_size;
    const float* x  = (const float*)d_in[0];
    const float* Wq = (const float*)d_in[1];
    const float* Wo = (const float*)d_in[2];
    const float* lg = (const float*)d_in[3];
    float* out = (float*)d_out;

    const size_t SZ = (size_t)NB * NH * NL * DKH;
    unsigned short* xb  = (unsigned short*)d_ws;
    unsigned short* Wqb = xb + SZ;
    unsigned short* Wob = Wqb + (size_t)3 * ND * ND;
    unsigned short* Qb  = Wob + (size_t)ND * ND;
    unsigned short* Kb  = Qb + SZ;
    unsigned short* Vb  = Kb + SZ;
    unsigned short* SL  = Vb + SZ;
    unsigned short* SS  = SL + SZ;
    unsigned short* Ybb = SS + SZ;

    k_cast_all<<<2048, 256, 0, stream>>>(x, Wq, Wo, xb, Wqb, Wob);
    k_gemm_qkv_bf16<<<dim3(3 * ND / 128, NM / 128), 256, 0, stream>>>(xb, Wqb, Qb, Kb, Vb);
    k_chunk_state<<<dim3(NB * NH * NCH), 256, 0, stream>>>(Kb, Vb, lg, SL);
    k_scan<<<dim3(NB * NH, 16), 64, 0, stream>>>(SL, lg, SS);
    k_chunk_out<<<dim3(NB * NH * NCH), 256, 0, stream>>>(Qb, Kb, Vb, SS, lg, Ybb);
    k_gemm_out_bf16<<<dim3(ND / 128, NM / 128), 256, 0, stream>>>(Ybb, Wob, out);
}